// Round 1
// baseline (737.758 us; speedup 1.0000x reference)
//
#include <hip/hip_runtime.h>
#include <hip/hip_bf16.h>

#define NB 4
#define NQ 4096
#define CI 256
#define CO 256
#define NS 8
#define HFEAT 128
#define WFEAT 128
#define NPIX (HFEAT * WFEAT)

// ---------------------------------------------------------------------------
// loc = tanh(queries @ W_loc + b_loc)   [16384 rows][16 cols]
// 16 rows per block, 16 threads per row.
__global__ __launch_bounds__(256) void k_loc(const float* __restrict__ q,
                                             const float* __restrict__ Wl,
                                             const float* __restrict__ bl,
                                             float* __restrict__ loc) {
    int t = threadIdx.x;
    int row = blockIdx.x * 16 + (t >> 4);
    int col = t & 15;
    const float* qr = q + (size_t)row * CI;
    float acc = bl[col];
#pragma unroll 8
    for (int c = 0; c < CI; ++c) acc = fmaf(qr[c], Wl[c * 16 + col], acc);
    loc[(size_t)row * 16 + col] = tanhf(acc);
}

// ---------------------------------------------------------------------------
// out[r][o] = bias[o] + sum_c X[r][c] * W[c][o]
// 64 rows per block, 256 threads, thread computes 8 o x 8 rows.
__global__ __launch_bounds__(256) void k_gemm_rows(const float* __restrict__ X,
                                                   const float* __restrict__ W,
                                                   const float* __restrict__ bias,
                                                   float* __restrict__ out) {
    __shared__ float XT[CI][65];  // [c][row_local], +1 pad -> conflict-free
    int t = threadIdx.x;
    int row0 = blockIdx.x * 64;

#pragma unroll 8
    for (int i = 0; i < 64; ++i) {
        XT[t][i] = X[(size_t)(row0 + i) * CI + t];
    }
    __syncthreads();

    int o0 = (t >> 3) << 3;   // 32 groups of 8 outputs -> 256 outputs
    int r0 = (t & 7) << 3;    // 8 groups of 8 rows -> 64 rows

    float acc[8][8];
#pragma unroll
    for (int j = 0; j < 8; ++j) {
        float bj = bias[o0 + j];
#pragma unroll
        for (int i = 0; i < 8; ++i) acc[j][i] = bj;
    }

    for (int c = 0; c < CI; ++c) {
        const float4* wp = reinterpret_cast<const float4*>(W + (size_t)c * CO + o0);
        float4 wa = wp[0], wb = wp[1];
        float w[8] = {wa.x, wa.y, wa.z, wa.w, wb.x, wb.y, wb.z, wb.w};
        float x[8];
#pragma unroll
        for (int i = 0; i < 8; ++i) x[i] = XT[c][r0 + i];
#pragma unroll
        for (int j = 0; j < 8; ++j)
#pragma unroll
            for (int i = 0; i < 8; ++i)
                acc[j][i] = fmaf(x[i], w[j], acc[j][i]);
    }

#pragma unroll
    for (int i = 0; i < 8; ++i) {
        float4 s0 = make_float4(acc[0][i], acc[1][i], acc[2][i], acc[3][i]);
        float4 s1 = make_float4(acc[4][i], acc[5][i], acc[6][i], acc[7][i]);
        float4* op = reinterpret_cast<float4*>(out + (size_t)(row0 + r0 + i) * CO + o0);
        op[0] = s0;
        op[1] = s1;
    }
}

// ---------------------------------------------------------------------------
// 1x1 conv projection: out[b][pix][o] = bias[o] + sum_c W[o][c] * X[b][c][pix]
// stored bf16, pixel-major so the sampling gather is coalesced.
// Block: 64 pixels x 256 outputs; thread: 8 o x 8 pixels.
__global__ __launch_bounds__(256) void k_proj(const float* __restrict__ X,   // [NB][CI][NPIX]
                                              const float* __restrict__ W,   // [CO][CI]
                                              const float* __restrict__ bias,
                                              __hip_bfloat16* __restrict__ out) {  // [NB][NPIX][CO]
    __shared__ float Xs[CI][64];     // [c][pix_local]
    __shared__ float Ws[32][257];    // [ci][swizzled o], chunk of 32 c

    int t = threadIdx.x;
    int bb = blockIdx.x >> 8;            // batch
    int p0 = (blockIdx.x & 255) * 64;    // pixel tile
    int lane = t & 63;
    int wv = t >> 6;

    // stage X tile: 256 c x 64 pixels
#pragma unroll 8
    for (int i = 0; i < 64; ++i) {
        int c = i * 4 + wv;
        Xs[c][lane] = X[((size_t)bb * CI + c) * NPIX + p0 + lane];
    }

    int o0 = (t >> 3) << 3;
    int p0l = (t & 7) << 3;
    int wcol[8];
#pragma unroll
    for (int j = 0; j < 8; ++j) {
        int o = o0 + j;
        wcol[j] = o ^ (o >> 2);  // bank-spread swizzle (bijective on [0,256))
    }

    float acc[8][8];
#pragma unroll
    for (int j = 0; j < 8; ++j) {
        float bj = bias[o0 + j];
#pragma unroll
        for (int i = 0; i < 8; ++i) acc[j][i] = bj;
    }

    int ciL = t & 31;
    int ohi = t >> 5;  // 0..7
    for (int cc = 0; cc < 8; ++cc) {
        __syncthreads();  // covers Xs staging on first iter, Ws reuse after
        // stage W chunk: 32 c x 256 o (swizzled columns)
#pragma unroll 4
        for (int jj = 0; jj < 32; ++jj) {
            int o = jj * 8 + ohi;
            Ws[ciL][o ^ (o >> 2)] = W[(size_t)o * CI + cc * 32 + ciL];
        }
        __syncthreads();

        for (int ci = 0; ci < 32; ++ci) {
            int c = cc * 32 + ci;
            float w[8];
#pragma unroll
            for (int j = 0; j < 8; ++j) w[j] = Ws[ci][wcol[j]];
            const float4* xr = reinterpret_cast<const float4*>(&Xs[c][p0l]);
            float4 xa = xr[0], xb = xr[1];
            float x[8] = {xa.x, xa.y, xa.z, xa.w, xb.x, xb.y, xb.z, xb.w};
#pragma unroll
            for (int j = 0; j < 8; ++j)
#pragma unroll
                for (int i = 0; i < 8; ++i)
                    acc[j][i] = fmaf(x[i], w[j], acc[j][i]);
        }
    }

    // epilogue: bf16, pixel-major, 16B vector stores
#pragma unroll
    for (int i = 0; i < 8; ++i) {
        int pix = p0 + p0l + i;
        union {
            uint4 u;
            __hip_bfloat16 h[8];
        } pk;
#pragma unroll
        for (int j = 0; j < 8; ++j) pk.h[j] = __float2bfloat16(acc[j][i]);
        *reinterpret_cast<uint4*>(&out[((size_t)bb * NPIX + pix) * CO + o0]) = pk.u;
    }
}

// ---------------------------------------------------------------------------
// Deformable sampling + per-query attention over S=8 points.
// One block per (b,q); thread = channel; head = 32-lane group.
__global__ __launch_bounds__(256) void k_attn(const __hip_bfloat16* __restrict__ kp,
                                              const __hip_bfloat16* __restrict__ vp,
                                              const float* __restrict__ qh,
                                              const float* __restrict__ loc,
                                              float* __restrict__ aout) {
    int bq = blockIdx.x;
    int b = bq >> 12;  // Q = 4096
    int t = threadIdx.x;

    float qv = qh[(size_t)bq * CO + t];
    const __hip_bfloat16* kb = kp + (size_t)b * NPIX * CO;
    const __hip_bfloat16* vb = vp + (size_t)b * NPIX * CO;

    float vss[NS], lg[NS];

#pragma unroll
    for (int s = 0; s < NS; ++s) {
        float x = loc[(size_t)bq * (NS * 2) + 2 * s];
        float y = loc[(size_t)bq * (NS * 2) + 2 * s + 1];
        float gx = (x + 1.f) * (WFEAT * 0.5f) - 0.5f;
        float gy = (y + 1.f) * (HFEAT * 0.5f) - 0.5f;
        float x0f = floorf(gx), y0f = floorf(gy);
        int x0 = (int)x0f, y0 = (int)y0f;
        float wx1 = gx - x0f, wy1 = gy - y0f;
        float wx0 = 1.f - wx1, wy0 = 1.f - wy1;
        bool xa = (x0 >= 0) && (x0 < WFEAT);
        bool xb = (x0 + 1 >= 0) && (x0 + 1 < WFEAT);
        bool ya = (y0 >= 0) && (y0 < HFEAT);
        bool yb = (y0 + 1 >= 0) && (y0 + 1 < HFEAT);
        int i00 = y0 * WFEAT + x0;

        float k00 = 0.f, k01 = 0.f, k10 = 0.f, k11 = 0.f;
        float v00 = 0.f, v01 = 0.f, v10 = 0.f, v11 = 0.f;
        if (xa && ya) {
            size_t idx = (size_t)i00 * CO + t;
            k00 = __bfloat162float(kb[idx]);
            v00 = __bfloat162float(vb[idx]);
        }
        if (xb && ya) {
            size_t idx = (size_t)(i00 + 1) * CO + t;
            k01 = __bfloat162float(kb[idx]);
            v01 = __bfloat162float(vb[idx]);
        }
        if (xa && yb) {
            size_t idx = (size_t)(i00 + WFEAT) * CO + t;
            k10 = __bfloat162float(kb[idx]);
            v10 = __bfloat162float(vb[idx]);
        }
        if (xb && yb) {
            size_t idx = (size_t)(i00 + WFEAT + 1) * CO + t;
            k11 = __bfloat162float(kb[idx]);
            v11 = __bfloat162float(vb[idx]);
        }

        float ks = (k00 * wx0 + k01 * wx1) * wy0 + (k10 * wx0 + k11 * wx1) * wy1;
        float vs = (v00 * wx0 + v01 * wx1) * wy0 + (v10 * wx0 + v11 * wx1) * wy1;
        vss[s] = vs;

        float p = qv * ks;
#pragma unroll
        for (int m = 16; m >= 1; m >>= 1) p += __shfl_xor(p, m, 32);
        lg[s] = p * 0.0625f;  // 1/sqrt(256)
    }

    float mx = lg[0];
#pragma unroll
    for (int s = 1; s < NS; ++s) mx = fmaxf(mx, lg[s]);
    float e[NS], sum = 0.f;
#pragma unroll
    for (int s = 0; s < NS; ++s) {
        e[s] = expf(lg[s] - mx);
        sum += e[s];
    }
    float inv = 1.f / sum;
    float o = 0.f;
#pragma unroll
    for (int s = 0; s < NS; ++s) o += vss[s] * e[s];
    o *= inv;

    aout[(size_t)bq * CO + t] = o;
}

// ---------------------------------------------------------------------------
extern "C" void kernel_launch(void* const* d_in, const int* in_sizes, int n_in,
                              void* d_out, int out_size, void* d_ws, size_t ws_size,
                              hipStream_t stream) {
    (void)in_sizes; (void)n_in; (void)out_size; (void)ws_size;
    const float* queries = (const float*)d_in[0];
    const float* keys    = (const float*)d_in[1];
    const float* values  = (const float*)d_in[2];
    const float* W_loc   = (const float*)d_in[3];
    const float* b_loc   = (const float*)d_in[4];
    const float* W_q     = (const float*)d_in[5];
    const float* b_q     = (const float*)d_in[6];
    const float* W_k     = (const float*)d_in[7];
    const float* b_k     = (const float*)d_in[8];
    const float* W_v     = (const float*)d_in[9];
    const float* b_v     = (const float*)d_in[10];
    const float* W_o     = (const float*)d_in[11];
    const float* b_o     = (const float*)d_in[12];
    float* out = (float*)d_out;

    char* ws = (char*)d_ws;
    __hip_bfloat16* kp = (__hip_bfloat16*)(ws);                 // 32 MB
    __hip_bfloat16* vp = (__hip_bfloat16*)(ws + 33554432);      // 32 MB
    float* qh   = (float*)(ws + 67108864);                      // 16 MB
    float* aout = (float*)(ws + 83886080);                      // 16 MB
    float* locb = (float*)(ws + 100663296);                     // 1 MB

    k_loc<<<dim3(1024), dim3(256), 0, stream>>>(queries, W_loc, b_loc, locb);
    k_gemm_rows<<<dim3(256), dim3(256), 0, stream>>>(queries, W_q, b_q, qh);
    k_proj<<<dim3(1024), dim3(256), 0, stream>>>(keys, W_k, b_k, kp);
    k_proj<<<dim3(1024), dim3(256), 0, stream>>>(values, W_v, b_v, vp);
    k_attn<<<dim3(NB * NQ), dim3(256), 0, stream>>>(kp, vp, qh, locb, aout);
    k_gemm_rows<<<dim3(256), dim3(256), 0, stream>>>(aout, W_o, b_o, out);
}

// Round 2
// 280.787 us; speedup vs baseline: 2.6275x; 2.6275x over previous
//
#include <hip/hip_runtime.h>
#include <hip/hip_bf16.h>

#define NB 4
#define NQ 4096
#define CI 256
#define CO 256
#define NS 8
#define HFEAT 128
#define WFEAT 128
#define NPIX (HFEAT * WFEAT)

typedef short bf16x8 __attribute__((ext_vector_type(8)));
typedef float f32x4 __attribute__((ext_vector_type(4)));

__device__ __forceinline__ unsigned short f2b(float x) {
    union { float f; unsigned u; } v; v.f = x;
    unsigned r = v.u + 0x7fff + ((v.u >> 16) & 1);
    return (unsigned short)(r >> 16);
}
__device__ __forceinline__ float b2f(unsigned short x) {
    union { unsigned u; float f; } v; v.u = ((unsigned)x) << 16;
    return v.f;
}
__device__ __forceinline__ void gload16(const void* g, void* l) {
    __builtin_amdgcn_global_load_lds((const __attribute__((address_space(1))) void*)g,
                                     (__attribute__((address_space(3))) void*)l, 16, 0, 0);
}

// ---------------------------------------------------------------------------
// Weight prep: Wk, Wv are [o][c] -> bf16 copy. Wq, Wo are [c][o] -> bf16 [o][c].
__global__ __launch_bounds__(256) void k_prep_w(const float* __restrict__ Wk,
                                                const float* __restrict__ Wv,
                                                const float* __restrict__ Wq,
                                                const float* __restrict__ Wo,
                                                unsigned short* __restrict__ out) {
    int mat = blockIdx.y;
    int base = blockIdx.x * 1024 + threadIdx.x * 4;
    const float* src = (mat == 0) ? Wk : (mat == 1) ? Wv : (mat == 2) ? Wq : Wo;
    unsigned short* dst = out + (size_t)mat * 65536;
    if (mat < 2) {
#pragma unroll
        for (int i = 0; i < 4; ++i) dst[base + i] = f2b(src[base + i]);
    } else {
#pragma unroll
        for (int i = 0; i < 4; ++i) {
            int oi = base + i;
            int o = oi >> 8, c = oi & 255;
            dst[oi] = f2b(src[c * 256 + o]);  // transpose
        }
    }
}

// ---------------------------------------------------------------------------
// queries fp32 -> bf16 (no transpose; already [m][k])
__global__ __launch_bounds__(256) void k_cvt(const float* __restrict__ in,
                                             unsigned short* __restrict__ out) {
    size_t i = ((size_t)blockIdx.x * 256 + threadIdx.x) * 8;
    float4 a = *reinterpret_cast<const float4*>(in + i);
    float4 b = *reinterpret_cast<const float4*>(in + i + 4);
    union { uint2 u2[2]; unsigned short h[8]; } pk;
    pk.h[0] = f2b(a.x); pk.h[1] = f2b(a.y); pk.h[2] = f2b(a.z); pk.h[3] = f2b(a.w);
    pk.h[4] = f2b(b.x); pk.h[5] = f2b(b.y); pk.h[6] = f2b(b.z); pk.h[7] = f2b(b.w);
    *reinterpret_cast<uint4*>(out + i) = *reinterpret_cast<uint4*>(&pk);
}

// ---------------------------------------------------------------------------
// keys/values [B][CI][NPIX] fp32 -> [B][NPIX][CI] bf16
__global__ __launch_bounds__(256) void k_transpose(const float* __restrict__ in,
                                                   unsigned short* __restrict__ out) {
    __shared__ float tile[64][65];
    int t = threadIdx.x;
    int p0 = blockIdx.x * 64;
    int c0 = blockIdx.y * 64;
    int b = blockIdx.z;
    int pl = t & 63, ch = t >> 6;
#pragma unroll 4
    for (int i = 0; i < 16; ++i) {
        tile[i * 4 + ch][pl] = in[((size_t)b * CI + c0 + i * 4 + ch) * NPIX + p0 + pl];
    }
    __syncthreads();
    int cl = t & 63, ph = t >> 6;
#pragma unroll 4
    for (int i = 0; i < 16; ++i) {
        int p = i * 4 + ph;
        out[((size_t)b * NPIX + p0 + p) * CI + c0 + cl] = f2b(tile[cl][p]);
    }
}

// ---------------------------------------------------------------------------
// loc = tanh(queries @ W_loc + b_loc)
__global__ __launch_bounds__(256) void k_loc(const float* __restrict__ q,
                                             const float* __restrict__ Wl,
                                             const float* __restrict__ bl,
                                             float* __restrict__ loc) {
    int t = threadIdx.x;
    int row = blockIdx.x * 16 + (t >> 4);
    int col = t & 15;
    const float* qr = q + (size_t)row * CI;
    float acc = bl[col];
#pragma unroll 8
    for (int c = 0; c < CI; ++c) acc = fmaf(qr[c], Wl[c * 16 + col], acc);
    loc[(size_t)row * 16 + col] = tanhf(acc);
}

// ---------------------------------------------------------------------------
// MFMA GEMM (m97 structure): C[M][256] = A[M][256] * Bt[256][256]^T + bias
// A bf16 [m][k], Bt bf16 [n][k]. 128x128 tile, BK=32, 4 waves (2x2), 4x4 frags.
template <int OUT_BF16>
__global__ __launch_bounds__(256) void k_gemm(const unsigned short* __restrict__ A,
                                              const unsigned short* __restrict__ Bt,
                                              const float* __restrict__ bias,
                                              void* __restrict__ outp) {
    __shared__ unsigned short As[128][32];
    __shared__ unsigned short Bs[128][32];
    int t = threadIdx.x;
    int w = t >> 6, l = t & 63;
    int bm = blockIdx.x >> 1, bc = blockIdx.x & 1;
    int m0 = bm * 128, n0 = bc * 128;
    int wr = w >> 1, wc = w & 1;

    f32x4 acc[4][4];
#pragma unroll
    for (int n = 0; n < 4; ++n) {
        float bv = bias[n0 + wc * 64 + n * 16 + (l & 15)];
#pragma unroll
        for (int m = 0; m < 4; ++m) acc[m][n] = f32x4{bv, bv, bv, bv};
    }

    int ar = wr * 64 + (l & 15);
    int br = wc * 64 + (l & 15);
    int kq = (l >> 4) * 8;
    // staging geometry: wave w covers rows w*32..w*32+31, 2 calls of 16 rows
    int srow = (l >> 2);          // 0..15 within the 16-row group
    int scol = (l & 3) * 8;       // k element offset within 32

    for (int kk = 0; kk < 8; ++kk) {
        int k0 = kk * 32;
#pragma unroll
        for (int j = 0; j < 2; ++j) {
            int row = w * 32 + j * 16 + srow;
            gload16(A + (size_t)(m0 + row) * CI + k0 + scol, &As[w * 32 + j * 16][0]);
            gload16(Bt + (size_t)(n0 + row) * CI + k0 + scol, &Bs[w * 32 + j * 16][0]);
        }
        __syncthreads();
        bf16x8 af[4], bfr[4];
#pragma unroll
        for (int m = 0; m < 4; ++m) af[m] = *reinterpret_cast<const bf16x8*>(&As[ar + m * 16][kq]);
#pragma unroll
        for (int n = 0; n < 4; ++n) bfr[n] = *reinterpret_cast<const bf16x8*>(&Bs[br + n * 16][kq]);
#pragma unroll
        for (int m = 0; m < 4; ++m)
#pragma unroll
            for (int n = 0; n < 4; ++n)
                acc[m][n] = __builtin_amdgcn_mfma_f32_16x16x32_bf16(af[m], bfr[n], acc[m][n], 0, 0, 0);
        __syncthreads();
    }

    int rbase = m0 + wr * 64 + (l >> 4) * 4;
    int cbase = n0 + wc * 64 + (l & 15);
#pragma unroll
    for (int m = 0; m < 4; ++m)
#pragma unroll
        for (int n = 0; n < 4; ++n)
#pragma unroll
            for (int r = 0; r < 4; ++r) {
                size_t row = rbase + m * 16 + r;
                size_t col = cbase + n * 16;
                if (OUT_BF16)
                    ((unsigned short*)outp)[row * CO + col] = f2b(acc[m][n][r]);
                else
                    ((float*)outp)[row * CO + col] = acc[m][n][r];
            }
}

// ---------------------------------------------------------------------------
// Deformable sampling + per-query attention. Block = (b,q); thread = channel.
__global__ __launch_bounds__(256) void k_attn(const unsigned short* __restrict__ kp,
                                              const unsigned short* __restrict__ vp,
                                              const unsigned short* __restrict__ qh,
                                              const float* __restrict__ loc,
                                              unsigned short* __restrict__ aout) {
    int bq = blockIdx.x;
    int b = bq >> 12;
    int t = threadIdx.x;

    float qv = b2f(qh[(size_t)bq * CO + t]);
    const unsigned short* kb = kp + (size_t)b * NPIX * CO;
    const unsigned short* vb = vp + (size_t)b * NPIX * CO;

    float vss[NS], lg[NS];

#pragma unroll
    for (int s = 0; s < NS; ++s) {
        float x = loc[(size_t)bq * (NS * 2) + 2 * s];
        float y = loc[(size_t)bq * (NS * 2) + 2 * s + 1];
        float gx = (x + 1.f) * (WFEAT * 0.5f) - 0.5f;
        float gy = (y + 1.f) * (HFEAT * 0.5f) - 0.5f;
        float x0f = floorf(gx), y0f = floorf(gy);
        int x0 = (int)x0f, y0 = (int)y0f;
        float wx1 = gx - x0f, wy1 = gy - y0f;
        float wx0 = 1.f - wx1, wy0 = 1.f - wy1;
        bool xa = (x0 >= 0) && (x0 < WFEAT);
        bool xb = (x0 + 1 >= 0) && (x0 + 1 < WFEAT);
        bool ya = (y0 >= 0) && (y0 < HFEAT);
        bool yb = (y0 + 1 >= 0) && (y0 + 1 < HFEAT);
        int i00 = y0 * WFEAT + x0;

        float k00 = 0.f, k01 = 0.f, k10 = 0.f, k11 = 0.f;
        float v00 = 0.f, v01 = 0.f, v10 = 0.f, v11 = 0.f;
        if (xa && ya) { size_t idx = (size_t)i00 * CO + t;            k00 = b2f(kb[idx]); v00 = b2f(vb[idx]); }
        if (xb && ya) { size_t idx = (size_t)(i00 + 1) * CO + t;      k01 = b2f(kb[idx]); v01 = b2f(vb[idx]); }
        if (xa && yb) { size_t idx = (size_t)(i00 + WFEAT) * CO + t;  k10 = b2f(kb[idx]); v10 = b2f(vb[idx]); }
        if (xb && yb) { size_t idx = (size_t)(i00 + WFEAT + 1) * CO + t; k11 = b2f(kb[idx]); v11 = b2f(vb[idx]); }

        float ks = (k00 * wx0 + k01 * wx1) * wy0 + (k10 * wx0 + k11 * wx1) * wy1;
        float vs = (v00 * wx0 + v01 * wx1) * wy0 + (v10 * wx0 + v11 * wx1) * wy1;
        vss[s] = vs;

        float p = qv * ks;
#pragma unroll
        for (int m = 16; m >= 1; m >>= 1) p += __shfl_xor(p, m, 32);
        lg[s] = p * 0.0625f;  // 1/sqrt(256)
    }

    float mx = lg[0];
#pragma unroll
    for (int s = 1; s < NS; ++s) mx = fmaxf(mx, lg[s]);
    float e[NS], sum = 0.f;
#pragma unroll
    for (int s = 0; s < NS; ++s) { e[s] = expf(lg[s] - mx); sum += e[s]; }
    float inv = 1.f / sum;
    float o = 0.f;
#pragma unroll
    for (int s = 0; s < NS; ++s) o += vss[s] * e[s];
    o *= inv;

    aout[(size_t)bq * CO + t] = f2b(o);
}

// ---------------------------------------------------------------------------
extern "C" void kernel_launch(void* const* d_in, const int* in_sizes, int n_in,
                              void* d_out, int out_size, void* d_ws, size_t ws_size,
                              hipStream_t stream) {
    (void)in_sizes; (void)n_in; (void)out_size; (void)ws_size;
    const float* queries = (const float*)d_in[0];
    const float* keys    = (const float*)d_in[1];
    const float* values  = (const float*)d_in[2];
    const float* W_loc   = (const float*)d_in[3];
    const float* b_loc   = (const float*)d_in[4];
    const float* W_q     = (const float*)d_in[5];
    const float* b_q     = (const float*)d_in[6];
    const float* W_k     = (const float*)d_in[7];
    const float* b_k     = (const float*)d_in[8];
    const float* W_v     = (const float*)d_in[9];
    const float* b_v     = (const float*)d_in[10];
    const float* W_o     = (const float*)d_in[11];
    const float* b_o     = (const float*)d_in[12];
    float* out = (float*)d_out;

    char* ws = (char*)d_ws;
    unsigned short* XtA  = (unsigned short*)(ws);                  // 32 MB (keys, then values)
    unsigned short* kp   = (unsigned short*)(ws + 33554432);       // 32 MB
    unsigned short* vp   = (unsigned short*)(ws + 67108864);       // 32 MB
    unsigned short* qbf  = (unsigned short*)(ws + 100663296);      // 8 MB
    unsigned short* aout = (unsigned short*)(ws + 100663296);      // 8 MB (reuses qbf, dead by then)
    unsigned short* qh   = (unsigned short*)(ws + 109051904);      // 8 MB
    float* locb          = (float*)(ws + 117440512);               // 1 MB
    unsigned short* wbuf = (unsigned short*)(ws + 118489088);      // 512 KB

    k_prep_w<<<dim3(64, 4), 256, 0, stream>>>(W_k, W_v, W_q, W_o, wbuf);
    k_cvt<<<dim3(2048), 256, 0, stream>>>(queries, qbf);
    k_loc<<<dim3(1024), 256, 0, stream>>>(queries, W_loc, b_loc, locb);
    k_gemm<1><<<dim3(256), 256, 0, stream>>>(qbf, wbuf + 131072, b_q, qh);

    k_transpose<<<dim3(256, 4, NB), 256, 0, stream>>>(keys, XtA);
    k_gemm<1><<<dim3(1024), 256, 0, stream>>>(XtA, wbuf, b_k, kp);
    k_transpose<<<dim3(256, 4, NB), 256, 0, stream>>>(values, XtA);
    k_gemm<1><<<dim3(1024), 256, 0, stream>>>(XtA, wbuf + 65536, b_v, vp);

    k_attn<<<dim3(NB * NQ), 256, 0, stream>>>(kp, vp, qh, locb, aout);
    k_gemm<0><<<dim3(256), 256, 0, stream>>>(aout, wbuf + 196608, b_o, out);
}

// Round 3
// 177.992 us; speedup vs baseline: 4.1449x; 1.5775x over previous
//
#include <hip/hip_runtime.h>
#include <hip/hip_bf16.h>

#define NB 4
#define NQ 4096
#define CI 256
#define CO 256
#define NS 8
#define HFEAT 128
#define WFEAT 128
#define NPIX (HFEAT * WFEAT)

typedef short bf16x8 __attribute__((ext_vector_type(8)));
typedef float f32x4 __attribute__((ext_vector_type(4)));

__device__ __forceinline__ unsigned short f2b(float x) {
    union { float f; unsigned u; } v; v.f = x;
    unsigned r = v.u + 0x7fff + ((v.u >> 16) & 1);
    return (unsigned short)(r >> 16);
}
__device__ __forceinline__ float b2f(unsigned short x) {
    union { unsigned u; float f; } v; v.u = ((unsigned)x) << 16;
    return v.f;
}
// unpack uint (2 bf16) -> 2 floats: lo = bits<<16, hi = bits&0xffff0000
__device__ __forceinline__ void b2f2(unsigned u, float& a, float& b) {
    union { unsigned x; float f; } va, vb;
    va.x = u << 16;
    vb.x = u & 0xffff0000u;
    a = va.f; b = vb.f;
}
__device__ __forceinline__ void gload16(const void* g, void* l) {
    __builtin_amdgcn_global_load_lds((const __attribute__((address_space(1))) void*)g,
                                     (__attribute__((address_space(3))) void*)l, 16, 0, 0);
}

// ---------------------------------------------------------------------------
// Weight prep: Wk, Wv are [o][c] -> bf16 copy. Wq, Wo are [c][o] -> bf16 [o][c].
__global__ __launch_bounds__(256) void k_prep_w(const float* __restrict__ Wk,
                                                const float* __restrict__ Wv,
                                                const float* __restrict__ Wq,
                                                const float* __restrict__ Wo,
                                                unsigned short* __restrict__ out) {
    int mat = blockIdx.y;
    int base = blockIdx.x * 1024 + threadIdx.x * 4;
    const float* src = (mat == 0) ? Wk : (mat == 1) ? Wv : (mat == 2) ? Wq : Wo;
    unsigned short* dst = out + (size_t)mat * 65536;
    if (mat < 2) {
#pragma unroll
        for (int i = 0; i < 4; ++i) dst[base + i] = f2b(src[base + i]);
    } else {
#pragma unroll
        for (int i = 0; i < 4; ++i) {
            int oi = base + i;
            int o = oi >> 8, c = oi & 255;
            dst[oi] = f2b(src[c * 256 + o]);  // transpose
        }
    }
}

// ---------------------------------------------------------------------------
// queries fp32 -> bf16 (no transpose; already [m][k])
__global__ __launch_bounds__(256) void k_cvt(const float* __restrict__ in,
                                             unsigned short* __restrict__ out) {
    size_t i = ((size_t)blockIdx.x * 256 + threadIdx.x) * 8;
    float4 a = *reinterpret_cast<const float4*>(in + i);
    float4 b = *reinterpret_cast<const float4*>(in + i + 4);
    union { uint2 u2[2]; unsigned short h[8]; } pk;
    pk.h[0] = f2b(a.x); pk.h[1] = f2b(a.y); pk.h[2] = f2b(a.z); pk.h[3] = f2b(a.w);
    pk.h[4] = f2b(b.x); pk.h[5] = f2b(b.y); pk.h[6] = f2b(b.z); pk.h[7] = f2b(b.w);
    *reinterpret_cast<uint4*>(out + i) = *reinterpret_cast<uint4*>(&pk);
}

// ---------------------------------------------------------------------------
// keys/values [B][CI][NPIX] fp32 -> [B][NPIX][CI] bf16
__global__ __launch_bounds__(256) void k_transpose(const float* __restrict__ in,
                                                   unsigned short* __restrict__ out) {
    __shared__ float tile[64][65];
    int t = threadIdx.x;
    int p0 = blockIdx.x * 64;
    int c0 = blockIdx.y * 64;
    int b = blockIdx.z;
    int pl = t & 63, ch = t >> 6;
#pragma unroll 4
    for (int i = 0; i < 16; ++i) {
        tile[i * 4 + ch][pl] = in[((size_t)b * CI + c0 + i * 4 + ch) * NPIX + p0 + pl];
    }
    __syncthreads();
    int cl = t & 63, ph = t >> 6;
#pragma unroll 4
    for (int i = 0; i < 16; ++i) {
        int p = i * 4 + ph;
        out[((size_t)b * NPIX + p0 + p) * CI + c0 + cl] = f2b(tile[cl][p]);
    }
}

// ---------------------------------------------------------------------------
// loc = tanh(queries @ W_loc + b_loc)
__global__ __launch_bounds__(256) void k_loc(const float* __restrict__ q,
                                             const float* __restrict__ Wl,
                                             const float* __restrict__ bl,
                                             float* __restrict__ loc) {
    int t = threadIdx.x;
    int row = blockIdx.x * 16 + (t >> 4);
    int col = t & 15;
    const float* qr = q + (size_t)row * CI;
    float acc = bl[col];
#pragma unroll 8
    for (int c = 0; c < CI; ++c) acc = fmaf(qr[c], Wl[c * 16 + col], acc);
    loc[(size_t)row * 16 + col] = tanhf(acc);
}

// ---------------------------------------------------------------------------
// MFMA GEMM (m97 structure): C[M][256] = A[M][256] * Bt[256][256]^T + bias
// A bf16 [m][k], Bt bf16 [n][k]. 128x128 tile, BK=32, 4 waves (2x2), 4x4 frags.
template <int OUT_BF16>
__global__ __launch_bounds__(256) void k_gemm(const unsigned short* __restrict__ A,
                                              const unsigned short* __restrict__ Bt,
                                              const float* __restrict__ bias,
                                              void* __restrict__ outp) {
    __shared__ unsigned short As[128][32];
    __shared__ unsigned short Bs[128][32];
    int t = threadIdx.x;
    int w = t >> 6, l = t & 63;
    int bm = blockIdx.x >> 1, bc = blockIdx.x & 1;
    int m0 = bm * 128, n0 = bc * 128;
    int wr = w >> 1, wc = w & 1;

    f32x4 acc[4][4];
#pragma unroll
    for (int n = 0; n < 4; ++n) {
        float bv = bias[n0 + wc * 64 + n * 16 + (l & 15)];
#pragma unroll
        for (int m = 0; m < 4; ++m) acc[m][n] = f32x4{bv, bv, bv, bv};
    }

    int ar = wr * 64 + (l & 15);
    int br = wc * 64 + (l & 15);
    int kq = (l >> 4) * 8;
    int srow = (l >> 2);
    int scol = (l & 3) * 8;

    for (int kk = 0; kk < 8; ++kk) {
        int k0 = kk * 32;
#pragma unroll
        for (int j = 0; j < 2; ++j) {
            int row = w * 32 + j * 16 + srow;
            gload16(A + (size_t)(m0 + row) * CI + k0 + scol, &As[w * 32 + j * 16][0]);
            gload16(Bt + (size_t)(n0 + row) * CI + k0 + scol, &Bs[w * 32 + j * 16][0]);
        }
        __syncthreads();
        bf16x8 af[4], bfr[4];
#pragma unroll
        for (int m = 0; m < 4; ++m) af[m] = *reinterpret_cast<const bf16x8*>(&As[ar + m * 16][kq]);
#pragma unroll
        for (int n = 0; n < 4; ++n) bfr[n] = *reinterpret_cast<const bf16x8*>(&Bs[br + n * 16][kq]);
#pragma unroll
        for (int m = 0; m < 4; ++m)
#pragma unroll
            for (int n = 0; n < 4; ++n)
                acc[m][n] = __builtin_amdgcn_mfma_f32_16x16x32_bf16(af[m], bfr[n], acc[m][n], 0, 0, 0);
        __syncthreads();
    }

    int rbase = m0 + wr * 64 + (l >> 4) * 4;
    int cbase = n0 + wc * 64 + (l & 15);
#pragma unroll
    for (int m = 0; m < 4; ++m)
#pragma unroll
        for (int n = 0; n < 4; ++n)
#pragma unroll
            for (int r = 0; r < 4; ++r) {
                size_t row = rbase + m * 16 + r;
                size_t col = cbase + n * 16;
                if (OUT_BF16)
                    ((unsigned short*)outp)[row * CO + col] = f2b(acc[m][n][r]);
                else
                    ((float*)outp)[row * CO + col] = acc[m][n][r];
            }
}

// ---------------------------------------------------------------------------
// Deformable sampling + attention. One WAVE per query, 4 channels per lane
// (uint2 = 4 bf16 = 8B/lane -> one 512B wave transaction per corner row).
// Head h = 32 ch = 8 lanes (l>>3); logit reduce = shfl_xor 1,2,4 (stays in
// group, leaves logit in ALL 8 lanes -> softmax weight needs no broadcast).
// Online softmax (running m, lsum, unnormalized o[4]) -> single pass, low VGPR.
__global__ __launch_bounds__(256) void k_attn(const unsigned short* __restrict__ kp,
                                              const unsigned short* __restrict__ vp,
                                              const unsigned short* __restrict__ qh,
                                              const float* __restrict__ loc,
                                              unsigned short* __restrict__ aout) {
    int t = threadIdx.x;
    int wv = t >> 6, l = t & 63;
    int bq = blockIdx.x * 4 + wv;
    int b = bq >> 12;

    float qv[4];
    {
        uint2 qr = *reinterpret_cast<const uint2*>(qh + (size_t)bq * CO + l * 4);
        b2f2(qr.x, qv[0], qv[1]);
        b2f2(qr.y, qv[2], qv[3]);
    }
    const unsigned short* kb = kp + (size_t)b * NPIX * CO;
    const unsigned short* vb = vp + (size_t)b * NPIX * CO;
    const float* lq = loc + (size_t)bq * (NS * 2);
    int choff = l * 4;

    float m = -3.0e38f, lsum = 0.f;
    float o0 = 0.f, o1 = 0.f, o2 = 0.f, o3 = 0.f;

#pragma unroll
    for (int s = 0; s < NS; ++s) {
        float x = lq[2 * s];
        float y = lq[2 * s + 1];
        float gx = (x + 1.f) * (WFEAT * 0.5f) - 0.5f;
        float gy = (y + 1.f) * (HFEAT * 0.5f) - 0.5f;
        float x0f = floorf(gx), y0f = floorf(gy);
        int x0 = (int)x0f, y0 = (int)y0f;
        float wx1 = gx - x0f, wy1 = gy - y0f;
        float wx0 = 1.f - wx1, wy0 = 1.f - wy1;
        bool xa = (x0 >= 0) && (x0 < WFEAT);
        bool xb = (x0 + 1 >= 0) && (x0 + 1 < WFEAT);
        bool ya = (y0 >= 0) && (y0 < HFEAT);
        bool yb = (y0 + 1 >= 0) && (y0 + 1 < HFEAT);
        size_t i00 = (size_t)(y0 * WFEAT + x0) * CO + choff;

        uint2 z = make_uint2(0u, 0u);
        uint2 k00 = z, k01 = z, k10 = z, k11 = z;
        uint2 v00 = z, v01 = z, v10 = z, v11 = z;
        if (xa && ya) { k00 = *(const uint2*)(kb + i00);                 v00 = *(const uint2*)(vb + i00); }
        if (xb && ya) { k01 = *(const uint2*)(kb + i00 + CO);            v01 = *(const uint2*)(vb + i00 + CO); }
        if (xa && yb) { k10 = *(const uint2*)(kb + i00 + WFEAT * CO);    v10 = *(const uint2*)(vb + i00 + WFEAT * CO); }
        if (xb && yb) { k11 = *(const uint2*)(kb + i00 + (WFEAT+1)*CO);  v11 = *(const uint2*)(vb + i00 + (WFEAT+1)*CO); }

        float a0, a1, b0, b1, c0, c1, d0, d1;
        float ks[4], vs[4];
        // k channels 0,1
        b2f2(k00.x, a0, a1); b2f2(k01.x, b0, b1); b2f2(k10.x, c0, c1); b2f2(k11.x, d0, d1);
        ks[0] = fmaf(fmaf(b0, wx1, a0 * wx0), wy0, fmaf(d0, wx1, c0 * wx0) * wy1);
        ks[1] = fmaf(fmaf(b1, wx1, a1 * wx0), wy0, fmaf(d1, wx1, c1 * wx0) * wy1);
        b2f2(k00.y, a0, a1); b2f2(k01.y, b0, b1); b2f2(k10.y, c0, c1); b2f2(k11.y, d0, d1);
        ks[2] = fmaf(fmaf(b0, wx1, a0 * wx0), wy0, fmaf(d0, wx1, c0 * wx0) * wy1);
        ks[3] = fmaf(fmaf(b1, wx1, a1 * wx0), wy0, fmaf(d1, wx1, c1 * wx0) * wy1);
        b2f2(v00.x, a0, a1); b2f2(v01.x, b0, b1); b2f2(v10.x, c0, c1); b2f2(v11.x, d0, d1);
        vs[0] = fmaf(fmaf(b0, wx1, a0 * wx0), wy0, fmaf(d0, wx1, c0 * wx0) * wy1);
        vs[1] = fmaf(fmaf(b1, wx1, a1 * wx0), wy0, fmaf(d1, wx1, c1 * wx0) * wy1);
        b2f2(v00.y, a0, a1); b2f2(v01.y, b0, b1); b2f2(v10.y, c0, c1); b2f2(v11.y, d0, d1);
        vs[2] = fmaf(fmaf(b0, wx1, a0 * wx0), wy0, fmaf(d0, wx1, c0 * wx0) * wy1);
        vs[3] = fmaf(fmaf(b1, wx1, a1 * wx0), wy0, fmaf(d1, wx1, c1 * wx0) * wy1);

        float p = fmaf(qv[0], ks[0], fmaf(qv[1], ks[1], fmaf(qv[2], ks[2], qv[3] * ks[3])));
        p += __shfl_xor(p, 1);
        p += __shfl_xor(p, 2);
        p += __shfl_xor(p, 4);
        float lg = p * 0.0625f;  // 1/sqrt(256)

        float nm = fmaxf(m, lg);
        float sc = __expf(m - nm);   // first iter: exp(-3e38) = 0
        float w = __expf(lg - nm);
        lsum = fmaf(lsum, sc, w);
        o0 = fmaf(o0, sc, w * vs[0]);
        o1 = fmaf(o1, sc, w * vs[1]);
        o2 = fmaf(o2, sc, w * vs[2]);
        o3 = fmaf(o3, sc, w * vs[3]);
        m = nm;
    }

    float inv = 1.f / lsum;
    uint2 pk;
    pk.x = ((unsigned)f2b(o0 * inv)) | (((unsigned)f2b(o1 * inv)) << 16);
    pk.y = ((unsigned)f2b(o2 * inv)) | (((unsigned)f2b(o3 * inv)) << 16);
    *reinterpret_cast<uint2*>(aout + (size_t)bq * CO + choff) = pk;
}

// ---------------------------------------------------------------------------
extern "C" void kernel_launch(void* const* d_in, const int* in_sizes, int n_in,
                              void* d_out, int out_size, void* d_ws, size_t ws_size,
                              hipStream_t stream) {
    (void)in_sizes; (void)n_in; (void)out_size; (void)ws_size;
    const float* queries = (const float*)d_in[0];
    const float* keys    = (const float*)d_in[1];
    const float* values  = (const float*)d_in[2];
    const float* W_loc   = (const float*)d_in[3];
    const float* b_loc   = (const float*)d_in[4];
    const float* W_q     = (const float*)d_in[5];
    const float* b_q     = (const float*)d_in[6];
    const float* W_k     = (const float*)d_in[7];
    const float* b_k     = (const float*)d_in[8];
    const float* W_v     = (const float*)d_in[9];
    const float* b_v     = (const float*)d_in[10];
    const float* W_o     = (const float*)d_in[11];
    const float* b_o     = (const float*)d_in[12];
    float* out = (float*)d_out;

    char* ws = (char*)d_ws;
    unsigned short* XtA  = (unsigned short*)(ws);                  // 32 MB (keys, then values)
    unsigned short* kp   = (unsigned short*)(ws + 33554432);       // 32 MB
    unsigned short* vp   = (unsigned short*)(ws + 67108864);       // 32 MB
    unsigned short* qbf  = (unsigned short*)(ws + 100663296);      // 8 MB
    unsigned short* aout = (unsigned short*)(ws + 100663296);      // 8 MB (reuses qbf, dead by then)
    unsigned short* qh   = (unsigned short*)(ws + 109051904);      // 8 MB
    float* locb          = (float*)(ws + 117440512);               // 1 MB
    unsigned short* wbuf = (unsigned short*)(ws + 118489088);      // 512 KB

    k_prep_w<<<dim3(64, 4), 256, 0, stream>>>(W_k, W_v, W_q, W_o, wbuf);
    k_cvt<<<dim3(2048), 256, 0, stream>>>(queries, qbf);
    k_loc<<<dim3(1024), 256, 0, stream>>>(queries, W_loc, b_loc, locb);
    k_gemm<1><<<dim3(256), 256, 0, stream>>>(qbf, wbuf + 131072, b_q, qh);

    k_transpose<<<dim3(256, 4, NB), 256, 0, stream>>>(keys, XtA);
    k_gemm<1><<<dim3(1024), 256, 0, stream>>>(XtA, wbuf, b_k, kp);
    k_transpose<<<dim3(256, 4, NB), 256, 0, stream>>>(values, XtA);
    k_gemm<1><<<dim3(1024), 256, 0, stream>>>(XtA, wbuf + 65536, b_v, vp);

    k_attn<<<dim3(NB * NQ / 4), 256, 0, stream>>>(kp, vp, qh, locb, aout);
    k_gemm<0><<<dim3(256), 256, 0, stream>>>(aout, wbuf + 196608, b_o, out);
}

// Round 4
// 128.264 us; speedup vs baseline: 5.7519x; 1.3877x over previous
//
#include <hip/hip_runtime.h>
#include <hip/hip_bf16.h>

#define NB 4
#define NQ 4096
#define CI 256
#define CO 256
#define NS 8
#define HFEAT 128
#define WFEAT 128
#define NPIX (HFEAT * WFEAT)

typedef short bf16x8 __attribute__((ext_vector_type(8)));
typedef float f32x4 __attribute__((ext_vector_type(4)));

__device__ __forceinline__ unsigned short f2b(float x) {
    union { float f; unsigned u; } v; v.f = x;
    unsigned r = v.u + 0x7fff + ((v.u >> 16) & 1);
    return (unsigned short)(r >> 16);
}
__device__ __forceinline__ float b2f(unsigned short x) {
    union { unsigned u; float f; } v; v.u = ((unsigned)x) << 16;
    return v.f;
}
__device__ __forceinline__ void b2f2(unsigned u, float& a, float& b) {
    union { unsigned x; float f; } va, vb;
    va.x = u << 16;
    vb.x = u & 0xffff0000u;
    a = va.f; b = vb.f;
}
__device__ __forceinline__ void gload16(const void* g, void* l) {
    __builtin_amdgcn_global_load_lds((const __attribute__((address_space(1))) void*)g,
                                     (__attribute__((address_space(3))) void*)l, 16, 0, 0);
}

// ---------------------------------------------------------------------------
// Weight prep: Wk, Wv are [o][c] -> bf16 copy. Wq, Wo are [c][o] -> bf16 [o][c].
__global__ __launch_bounds__(256) void k_prep_w(const float* __restrict__ Wk,
                                                const float* __restrict__ Wv,
                                                const float* __restrict__ Wq,
                                                const float* __restrict__ Wo,
                                                unsigned short* __restrict__ out) {
    int mat = blockIdx.y;
    int base = blockIdx.x * 1024 + threadIdx.x * 4;
    const float* src = (mat == 0) ? Wk : (mat == 1) ? Wv : (mat == 2) ? Wq : Wo;
    unsigned short* dst = out + (size_t)mat * 65536;
    if (mat < 2) {
#pragma unroll
        for (int i = 0; i < 4; ++i) dst[base + i] = f2b(src[base + i]);
    } else {
#pragma unroll
        for (int i = 0; i < 4; ++i) {
            int oi = base + i;
            int o = oi >> 8, c = oi & 255;
            dst[oi] = f2b(src[c * 256 + o]);  // transpose
        }
    }
}

// ---------------------------------------------------------------------------
// queries fp32 -> bf16
__global__ __launch_bounds__(256) void k_cvt(const float* __restrict__ in,
                                             unsigned short* __restrict__ out) {
    size_t i = ((size_t)blockIdx.x * 256 + threadIdx.x) * 8;
    float4 a = *reinterpret_cast<const float4*>(in + i);
    float4 b = *reinterpret_cast<const float4*>(in + i + 4);
    union { uint2 u2[2]; unsigned short h[8]; } pk;
    pk.h[0] = f2b(a.x); pk.h[1] = f2b(a.y); pk.h[2] = f2b(a.z); pk.h[3] = f2b(a.w);
    pk.h[4] = f2b(b.x); pk.h[5] = f2b(b.y); pk.h[6] = f2b(b.z); pk.h[7] = f2b(b.w);
    *reinterpret_cast<uint4*>(out + i) = *reinterpret_cast<uint4*>(&pk);
}

// ---------------------------------------------------------------------------
// loc = tanh(q @ Wl + bl). 32 rows/block; q rows + Wl^T staged in LDS.
__global__ __launch_bounds__(256) void k_loc(const float* __restrict__ q,
                                             const float* __restrict__ Wl,
                                             const float* __restrict__ bl,
                                             float* __restrict__ loc) {
    __shared__ float qs[32][260];
    __shared__ float wlt[16][260];  // wlt[col][c]
    int t = threadIdx.x;
    int row0 = blockIdx.x * 32;
    {
        int rr = t >> 6;
        int c4 = (t & 63) * 4;
#pragma unroll
        for (int i = 0; i < 8; ++i) {
            int r = i * 4 + rr;
            *reinterpret_cast<float4*>(&qs[r][c4]) =
                *reinterpret_cast<const float4*>(q + (size_t)(row0 + r) * CI + c4);
        }
    }
    {
        int c = t;
#pragma unroll
        for (int col = 0; col < 16; ++col) wlt[col][c] = Wl[c * 16 + col];
    }
    __syncthreads();
    int r = t & 31;
    int cg = t >> 5;  // cols cg, cg+8
    float a0 = bl[cg], a1 = bl[cg + 8];
    for (int c4 = 0; c4 < 256; c4 += 4) {
        float4 qv = *reinterpret_cast<const float4*>(&qs[r][c4]);
        float4 w0 = *reinterpret_cast<const float4*>(&wlt[cg][c4]);
        float4 w1 = *reinterpret_cast<const float4*>(&wlt[cg + 8][c4]);
        a0 = fmaf(qv.x, w0.x, a0); a0 = fmaf(qv.y, w0.y, a0);
        a0 = fmaf(qv.z, w0.z, a0); a0 = fmaf(qv.w, w0.w, a0);
        a1 = fmaf(qv.x, w1.x, a1); a1 = fmaf(qv.y, w1.y, a1);
        a1 = fmaf(qv.z, w1.z, a1); a1 = fmaf(qv.w, w1.w, a1);
    }
    loc[(size_t)(row0 + r) * 16 + cg] = tanhf(a0);
    loc[(size_t)(row0 + r) * 16 + cg + 8] = tanhf(a1);
}

// ---------------------------------------------------------------------------
// MFMA GEMM (m97 structure): C[M][256] = A[M][256] * Bt[256][256]^T + bias
template <int OUT_BF16>
__global__ __launch_bounds__(256) void k_gemm(const unsigned short* __restrict__ A,
                                              const unsigned short* __restrict__ Bt,
                                              const float* __restrict__ bias,
                                              void* __restrict__ outp) {
    __shared__ unsigned short As[128][32];
    __shared__ unsigned short Bs[128][32];
    int t = threadIdx.x;
    int w = t >> 6, l = t & 63;
    int bm = blockIdx.x >> 1, bc = blockIdx.x & 1;
    int m0 = bm * 128, n0 = bc * 128;
    int wr = w >> 1, wc = w & 1;

    f32x4 acc[4][4];
#pragma unroll
    for (int n = 0; n < 4; ++n) {
        float bv = bias[n0 + wc * 64 + n * 16 + (l & 15)];
#pragma unroll
        for (int m = 0; m < 4; ++m) acc[m][n] = f32x4{bv, bv, bv, bv};
    }

    int ar = wr * 64 + (l & 15);
    int br = wc * 64 + (l & 15);
    int kq = (l >> 4) * 8;
    int srow = (l >> 2);
    int scol = (l & 3) * 8;

    for (int kk = 0; kk < 8; ++kk) {
        int k0 = kk * 32;
#pragma unroll
        for (int j = 0; j < 2; ++j) {
            int row = w * 32 + j * 16 + srow;
            gload16(A + (size_t)(m0 + row) * CI + k0 + scol, &As[w * 32 + j * 16][0]);
            gload16(Bt + (size_t)(n0 + row) * CI + k0 + scol, &Bs[w * 32 + j * 16][0]);
        }
        __syncthreads();
        bf16x8 af[4], bfr[4];
#pragma unroll
        for (int m = 0; m < 4; ++m) af[m] = *reinterpret_cast<const bf16x8*>(&As[ar + m * 16][kq]);
#pragma unroll
        for (int n = 0; n < 4; ++n) bfr[n] = *reinterpret_cast<const bf16x8*>(&Bs[br + n * 16][kq]);
#pragma unroll
        for (int m = 0; m < 4; ++m)
#pragma unroll
            for (int n = 0; n < 4; ++n)
                acc[m][n] = __builtin_amdgcn_mfma_f32_16x16x32_bf16(af[m], bfr[n], acc[m][n], 0, 0, 0);
        __syncthreads();
    }

    int rbase = m0 + wr * 64 + (l >> 4) * 4;
    int cbase = n0 + wc * 64 + (l & 15);
#pragma unroll
    for (int m = 0; m < 4; ++m)
#pragma unroll
        for (int n = 0; n < 4; ++n)
#pragma unroll
            for (int r = 0; r < 4; ++r) {
                size_t row = rbase + m * 16 + r;
                size_t col = cbase + n * 16;
                if (OUT_BF16)
                    ((unsigned short*)outp)[row * CO + col] = f2b(acc[m][n][r]);
                else
                    ((float*)outp)[row * CO + col] = acc[m][n][r];
            }
}

// ---------------------------------------------------------------------------
// Fused 1x1-conv projection: reads channel-major fp32 X directly, transposes
// during LDS staging (fp32->bf16, pair-packed b32 writes into padded As[128][40],
// pad 40 => 80B rows: b128-aligned reads, ~4-way write conflicts).
// Handles BOTH maps (keys->kp, values->vp) in one dispatch. XCD swizzle keeps
// the two o-halves of a pixel tile (shared A) on the same XCD.
__global__ __launch_bounds__(256) void k_proj(const float* __restrict__ keys,
                                              const float* __restrict__ values,
                                              const unsigned short* __restrict__ wbuf,
                                              const float* __restrict__ bK,
                                              const float* __restrict__ bV,
                                              unsigned short* __restrict__ kp,
                                              unsigned short* __restrict__ vp) {
    __shared__ unsigned short As[128][40];
    __shared__ unsigned short Bs[128][32];
    // XCD swizzle: xcd = blockIdx & 7 owns 256 consecutive logical tiles
    int blk = ((blockIdx.x & 7) << 8) | (blockIdx.x >> 3);  // 2048 = 8*256, bijective
    int map = blk >> 10;
    int rem = blk & 1023;
    int b = rem >> 8;
    int rem2 = rem & 255;
    int pix0 = (rem2 >> 1) * 128;
    int o0 = (rem2 & 1) * 128;
    const float* X = (map ? values : keys) + (size_t)b * (CI * NPIX);
    const unsigned short* W = wbuf + (size_t)map * 65536;
    const float* bias = map ? bV : bK;
    unsigned short* outp = (map ? vp : kp) + (size_t)b * (NPIX * CO);

    int t = threadIdx.x;
    int w = t >> 6, l = t & 63;
    int wr = w >> 1, wc = w & 1;

    f32x4 acc[4][4];
#pragma unroll
    for (int n = 0; n < 4; ++n) {
        float bv = bias[o0 + wc * 64 + n * 16 + (l & 15)];
#pragma unroll
        for (int m = 0; m < 4; ++m) acc[m][n] = f32x4{bv, bv, bv, bv};
    }

    int srow = l >> 2, scol = (l & 3) * 8;  // B staging (global_load_lds)
    int pl = t & 31;                        // pix lane (0..31)
    int ch = (t >> 5) * 2;                  // c-pair base (0,2,..,14)
    int ar = wr * 64 + (l & 15);
    int br = wc * 64 + (l & 15);
    int kq = (l >> 4) * 8;

    for (int kk = 0; kk < 8; ++kk) {
        int k0 = kk * 32;
        // B tile (bf16 W[o][c]) via async DMA
#pragma unroll
        for (int j = 0; j < 2; ++j) {
            int row = w * 32 + j * 16 + srow;
            gload16(W + (size_t)(o0 + row) * CI + k0 + scol, &Bs[w * 32 + j * 16][0]);
        }
        // A tile: fp32 loads (coalesced 128B runs per 32 lanes), convert,
        // transposed pair-packed writes into As[pix][c]
        float v0[2][4], v1[2][4];
#pragma unroll
        for (int i = 0; i < 2; ++i) {
            const float* xr0 = X + (size_t)(k0 + i * 16 + ch) * NPIX + pix0 + pl;
            const float* xr1 = xr0 + NPIX;
#pragma unroll
            for (int j = 0; j < 4; ++j) {
                v0[i][j] = xr0[j * 32];
                v1[i][j] = xr1[j * 32];
            }
        }
#pragma unroll
        for (int i = 0; i < 2; ++i)
#pragma unroll
            for (int j = 0; j < 4; ++j) {
                unsigned pkd = (unsigned)f2b(v0[i][j]) | ((unsigned)f2b(v1[i][j]) << 16);
                *reinterpret_cast<unsigned*>(&As[pl + j * 32][i * 16 + ch]) = pkd;
            }
        __syncthreads();
        bf16x8 af[4], bfr[4];
#pragma unroll
        for (int m = 0; m < 4; ++m) af[m] = *reinterpret_cast<const bf16x8*>(&As[ar + m * 16][kq]);
#pragma unroll
        for (int n = 0; n < 4; ++n) bfr[n] = *reinterpret_cast<const bf16x8*>(&Bs[br + n * 16][kq]);
#pragma unroll
        for (int m = 0; m < 4; ++m)
#pragma unroll
            for (int n = 0; n < 4; ++n)
                acc[m][n] = __builtin_amdgcn_mfma_f32_16x16x32_bf16(af[m], bfr[n], acc[m][n], 0, 0, 0);
        __syncthreads();
    }

    int rbase = wr * 64 + (l >> 4) * 4;
    int cbase = o0 + wc * 64 + (l & 15);
#pragma unroll
    for (int m = 0; m < 4; ++m)
#pragma unroll
        for (int n = 0; n < 4; ++n)
#pragma unroll
            for (int r = 0; r < 4; ++r) {
                size_t row = (size_t)pix0 + rbase + m * 16 + r;
                size_t col = cbase + n * 16;
                outp[row * CO + col] = f2b(acc[m][n][r]);
            }
}

// ---------------------------------------------------------------------------
// Deformable sampling + attention. One wave per query, 4 ch/lane (uint2 loads).
// XCD-batch clustering: XCD pair {2b,2b+1} owns batch b (L2 locality on maps).
__global__ __launch_bounds__(256) void k_attn(const unsigned short* __restrict__ kp,
                                              const unsigned short* __restrict__ vp,
                                              const unsigned short* __restrict__ qh,
                                              const float* __restrict__ loc,
                                              unsigned short* __restrict__ aout) {
    int t = threadIdx.x;
    int wv = t >> 6, l = t & 63;
    int blk = blockIdx.x;
    int xcd = blk & 7;
    int b = xcd >> 1;
    int idx = ((blk >> 3) << 1) | (xcd & 1);  // 0..1023, bijective
    int bq = (b << 12) | (idx << 2) | wv;

    float qv[4];
    {
        uint2 qr = *reinterpret_cast<const uint2*>(qh + (size_t)bq * CO + l * 4);
        b2f2(qr.x, qv[0], qv[1]);
        b2f2(qr.y, qv[2], qv[3]);
    }
    const unsigned short* kb = kp + (size_t)b * NPIX * CO;
    const unsigned short* vb = vp + (size_t)b * NPIX * CO;
    const float* lq = loc + (size_t)bq * (NS * 2);
    int choff = l * 4;

    float m = -3.0e38f, lsum = 0.f;
    float o0 = 0.f, o1 = 0.f, o2 = 0.f, o3 = 0.f;

#pragma unroll
    for (int s = 0; s < NS; ++s) {
        float x = lq[2 * s];
        float y = lq[2 * s + 1];
        float gx = (x + 1.f) * (WFEAT * 0.5f) - 0.5f;
        float gy = (y + 1.f) * (HFEAT * 0.5f) - 0.5f;
        float x0f = floorf(gx), y0f = floorf(gy);
        int x0 = (int)x0f, y0 = (int)y0f;
        float wx1 = gx - x0f, wy1 = gy - y0f;
        float wx0 = 1.f - wx1, wy0 = 1.f - wy1;
        bool xa = (x0 >= 0) && (x0 < WFEAT);
        bool xb = (x0 + 1 >= 0) && (x0 + 1 < WFEAT);
        bool ya = (y0 >= 0) && (y0 < HFEAT);
        bool yb = (y0 + 1 >= 0) && (y0 + 1 < HFEAT);
        size_t i00 = (size_t)(y0 * WFEAT + x0) * CO + choff;

        uint2 z = make_uint2(0u, 0u);
        uint2 k00 = z, k01 = z, k10 = z, k11 = z;
        uint2 v00 = z, v01 = z, v10 = z, v11 = z;
        if (xa && ya) { k00 = *(const uint2*)(kb + i00);                 v00 = *(const uint2*)(vb + i00); }
        if (xb && ya) { k01 = *(const uint2*)(kb + i00 + CO);            v01 = *(const uint2*)(vb + i00 + CO); }
        if (xa && yb) { k10 = *(const uint2*)(kb + i00 + WFEAT * CO);    v10 = *(const uint2*)(vb + i00 + WFEAT * CO); }
        if (xb && yb) { k11 = *(const uint2*)(kb + i00 + (WFEAT+1)*CO);  v11 = *(const uint2*)(vb + i00 + (WFEAT+1)*CO); }

        float a0, a1, b0, b1, c0, c1, d0, d1;
        float ks[4], vs[4];
        b2f2(k00.x, a0, a1); b2f2(k01.x, b0, b1); b2f2(k10.x, c0, c1); b2f2(k11.x, d0, d1);
        ks[0] = fmaf(fmaf(b0, wx1, a0 * wx0), wy0, fmaf(d0, wx1, c0 * wx0) * wy1);
        ks[1] = fmaf(fmaf(b1, wx1, a1 * wx0), wy0, fmaf(d1, wx1, c1 * wx0) * wy1);
        b2f2(k00.y, a0, a1); b2f2(k01.y, b0, b1); b2f2(k10.y, c0, c1); b2f2(k11.y, d0, d1);
        ks[2] = fmaf(fmaf(b0, wx1, a0 * wx0), wy0, fmaf(d0, wx1, c0 * wx0) * wy1);
        ks[3] = fmaf(fmaf(b1, wx1, a1 * wx0), wy0, fmaf(d1, wx1, c1 * wx0) * wy1);
        b2f2(v00.x, a0, a1); b2f2(v01.x, b0, b1); b2f2(v10.x, c0, c1); b2f2(v11.x, d0, d1);
        vs[0] = fmaf(fmaf(b0, wx1, a0 * wx0), wy0, fmaf(d0, wx1, c0 * wx0) * wy1);
        vs[1] = fmaf(fmaf(b1, wx1, a1 * wx0), wy0, fmaf(d1, wx1, c1 * wx0) * wy1);
        b2f2(v00.y, a0, a1); b2f2(v01.y, b0, b1); b2f2(v10.y, c0, c1); b2f2(v11.y, d0, d1);
        vs[2] = fmaf(fmaf(b0, wx1, a0 * wx0), wy0, fmaf(d0, wx1, c0 * wx0) * wy1);
        vs[3] = fmaf(fmaf(b1, wx1, a1 * wx0), wy0, fmaf(d1, wx1, c1 * wx0) * wy1);

        float p = fmaf(qv[0], ks[0], fmaf(qv[1], ks[1], fmaf(qv[2], ks[2], qv[3] * ks[3])));
        p += __shfl_xor(p, 1);
        p += __shfl_xor(p, 2);
        p += __shfl_xor(p, 4);
        float lg = p * 0.0625f;

        float nm = fmaxf(m, lg);
        float sc = __expf(m - nm);
        float wgt = __expf(lg - nm);
        lsum = fmaf(lsum, sc, wgt);
        o0 = fmaf(o0, sc, wgt * vs[0]);
        o1 = fmaf(o1, sc, wgt * vs[1]);
        o2 = fmaf(o2, sc, wgt * vs[2]);
        o3 = fmaf(o3, sc, wgt * vs[3]);
        m = nm;
    }

    float inv = 1.f / lsum;
    uint2 pk;
    pk.x = ((unsigned)f2b(o0 * inv)) | (((unsigned)f2b(o1 * inv)) << 16);
    pk.y = ((unsigned)f2b(o2 * inv)) | (((unsigned)f2b(o3 * inv)) << 16);
    *reinterpret_cast<uint2*>(aout + (size_t)bq * CO + choff) = pk;
}

// ---------------------------------------------------------------------------
extern "C" void kernel_launch(void* const* d_in, const int* in_sizes, int n_in,
                              void* d_out, int out_size, void* d_ws, size_t ws_size,
                              hipStream_t stream) {
    (void)in_sizes; (void)n_in; (void)out_size; (void)ws_size;
    const float* queries = (const float*)d_in[0];
    const float* keys    = (const float*)d_in[1];
    const float* values  = (const float*)d_in[2];
    const float* W_loc   = (const float*)d_in[3];
    const float* b_loc   = (const float*)d_in[4];
    const float* W_q     = (const float*)d_in[5];
    const float* b_q     = (const float*)d_in[6];
    const float* W_k     = (const float*)d_in[7];
    const float* b_k     = (const float*)d_in[8];
    const float* W_v     = (const float*)d_in[9];
    const float* b_v     = (const float*)d_in[10];
    const float* W_o     = (const float*)d_in[11];
    const float* b_o     = (const float*)d_in[12];
    float* out = (float*)d_out;

    char* ws = (char*)d_ws;
    unsigned short* kp   = (unsigned short*)(ws);                  // 32 MB
    unsigned short* vp   = (unsigned short*)(ws + 33554432);       // 32 MB
    unsigned short* qbf  = (unsigned short*)(ws + 67108864);       // 8 MB
    unsigned short* aout = (unsigned short*)(ws + 67108864);       // reuses qbf (dead by k_attn)
    unsigned short* qh   = (unsigned short*)(ws + 75497472);       // 8 MB
    float* locb          = (float*)(ws + 83886080);                // 1 MB
    unsigned short* wbuf = (unsigned short*)(ws + 84934656);       // 512 KB

    k_prep_w<<<dim3(64, 4), 256, 0, stream>>>(W_k, W_v, W_q, W_o, wbuf);
    k_cvt<<<dim3(2048), 256, 0, stream>>>(queries, qbf);
    k_loc<<<dim3(512), 256, 0, stream>>>(queries, W_loc, b_loc, locb);
    k_gemm<1><<<dim3(256), 256, 0, stream>>>(qbf, wbuf + 131072, b_q, qh);
    k_proj<<<dim3(2048), 256, 0, stream>>>(keys, values, wbuf, b_k, b_v, kp, vp);
    k_attn<<<dim3(NB * NQ / 4), 256, 0, stream>>>(kp, vp, qh, locb, aout);
    k_gemm<0><<<dim3(256), 256, 0, stream>>>(aout, wbuf + 196608, b_o, out);
}

// Round 5
// 124.229 us; speedup vs baseline: 5.9387x; 1.0325x over previous
//
#include <hip/hip_runtime.h>
#include <hip/hip_bf16.h>

#define NB 4
#define NQ 4096
#define CI 256
#define CO 256
#define NS 8
#define HFEAT 128
#define WFEAT 128
#define NPIX (HFEAT * WFEAT)

typedef short bf16x8 __attribute__((ext_vector_type(8)));
typedef float f32x4 __attribute__((ext_vector_type(4)));

__device__ __forceinline__ unsigned short f2b(float x) {
    union { float f; unsigned u; } v; v.f = x;
    unsigned r = v.u + 0x7fff + ((v.u >> 16) & 1);
    return (unsigned short)(r >> 16);
}
__device__ __forceinline__ float b2f(unsigned short x) {
    union { unsigned u; float f; } v; v.u = ((unsigned)x) << 16;
    return v.f;
}
__device__ __forceinline__ void b2f2(unsigned u, float& a, float& b) {
    union { unsigned x; float f; } va, vb;
    va.x = u << 16;
    vb.x = u & 0xffff0000u;
    a = va.f; b = vb.f;
}
__device__ __forceinline__ void gload16(const void* g, void* l) {
    __builtin_amdgcn_global_load_lds((const __attribute__((address_space(1))) void*)g,
                                     (__attribute__((address_space(3))) void*)l, 16, 0, 0);
}

// ---------------------------------------------------------------------------
// Weight prep: Wk, Wv are [o][c] -> bf16 copy. Wq, Wo are [c][o] -> bf16 [o][c].
__global__ __launch_bounds__(256) void k_prep_w(const float* __restrict__ Wk,
                                                const float* __restrict__ Wv,
                                                const float* __restrict__ Wq,
                                                const float* __restrict__ Wo,
                                                unsigned short* __restrict__ out) {
    int mat = blockIdx.y;
    int base = blockIdx.x * 1024 + threadIdx.x * 4;
    const float* src = (mat == 0) ? Wk : (mat == 1) ? Wv : (mat == 2) ? Wq : Wo;
    unsigned short* dst = out + (size_t)mat * 65536;
    if (mat < 2) {
#pragma unroll
        for (int i = 0; i < 4; ++i) dst[base + i] = f2b(src[base + i]);
    } else {
#pragma unroll
        for (int i = 0; i < 4; ++i) {
            int oi = base + i;
            int o = oi >> 8, c = oi & 255;
            dst[oi] = f2b(src[c * 256 + o]);  // transpose
        }
    }
}

// ---------------------------------------------------------------------------
// queries fp32 -> bf16
__global__ __launch_bounds__(256) void k_cvt(const float* __restrict__ in,
                                             unsigned short* __restrict__ out) {
    size_t i = ((size_t)blockIdx.x * 256 + threadIdx.x) * 8;
    float4 a = *reinterpret_cast<const float4*>(in + i);
    float4 b = *reinterpret_cast<const float4*>(in + i + 4);
    union { uint2 u2[2]; unsigned short h[8]; } pk;
    pk.h[0] = f2b(a.x); pk.h[1] = f2b(a.y); pk.h[2] = f2b(a.z); pk.h[3] = f2b(a.w);
    pk.h[4] = f2b(b.x); pk.h[5] = f2b(b.y); pk.h[6] = f2b(b.z); pk.h[7] = f2b(b.w);
    *reinterpret_cast<uint4*>(out + i) = *reinterpret_cast<uint4*>(&pk);
}

// ---------------------------------------------------------------------------
// loc = tanh(q @ Wl + bl). 32 rows/block; q rows + Wl^T staged in LDS.
__global__ __launch_bounds__(256) void k_loc(const float* __restrict__ q,
                                             const float* __restrict__ Wl,
                                             const float* __restrict__ bl,
                                             float* __restrict__ loc) {
    __shared__ float qs[32][260];
    __shared__ float wlt[16][260];  // wlt[col][c]
    int t = threadIdx.x;
    int row0 = blockIdx.x * 32;
    {
        int rr = t >> 6;
        int c4 = (t & 63) * 4;
#pragma unroll
        for (int i = 0; i < 8; ++i) {
            int r = i * 4 + rr;
            *reinterpret_cast<float4*>(&qs[r][c4]) =
                *reinterpret_cast<const float4*>(q + (size_t)(row0 + r) * CI + c4);
        }
    }
    {
        int c = t;
#pragma unroll
        for (int col = 0; col < 16; ++col) wlt[col][c] = Wl[c * 16 + col];
    }
    __syncthreads();
    int r = t & 31;
    int cg = t >> 5;  // cols cg, cg+8
    float a0 = bl[cg], a1 = bl[cg + 8];
    for (int c4 = 0; c4 < 256; c4 += 4) {
        float4 qv = *reinterpret_cast<const float4*>(&qs[r][c4]);
        float4 w0 = *reinterpret_cast<const float4*>(&wlt[cg][c4]);
        float4 w1 = *reinterpret_cast<const float4*>(&wlt[cg + 8][c4]);
        a0 = fmaf(qv.x, w0.x, a0); a0 = fmaf(qv.y, w0.y, a0);
        a0 = fmaf(qv.z, w0.z, a0); a0 = fmaf(qv.w, w0.w, a0);
        a1 = fmaf(qv.x, w1.x, a1); a1 = fmaf(qv.y, w1.y, a1);
        a1 = fmaf(qv.z, w1.z, a1); a1 = fmaf(qv.w, w1.w, a1);
    }
    loc[(size_t)(row0 + r) * 16 + cg] = tanhf(a0);
    loc[(size_t)(row0 + r) * 16 + cg + 8] = tanhf(a1);
}

// ---------------------------------------------------------------------------
// MFMA GEMM (m97 structure): C[M][256] = A[M][256] * Bt[256][256]^T + bias
template <int OUT_BF16>
__global__ __launch_bounds__(256) void k_gemm(const unsigned short* __restrict__ A,
                                              const unsigned short* __restrict__ Bt,
                                              const float* __restrict__ bias,
                                              void* __restrict__ outp) {
    __shared__ unsigned short As[128][32];
    __shared__ unsigned short Bs[128][32];
    int t = threadIdx.x;
    int w = t >> 6, l = t & 63;
    int bm = blockIdx.x >> 1, bc = blockIdx.x & 1;
    int m0 = bm * 128, n0 = bc * 128;
    int wr = w >> 1, wc = w & 1;

    f32x4 acc[4][4];
#pragma unroll
    for (int n = 0; n < 4; ++n) {
        float bv = bias[n0 + wc * 64 + n * 16 + (l & 15)];
#pragma unroll
        for (int m = 0; m < 4; ++m) acc[m][n] = f32x4{bv, bv, bv, bv};
    }

    int ar = wr * 64 + (l & 15);
    int br = wc * 64 + (l & 15);
    int kq = (l >> 4) * 8;
    int srow = (l >> 2);
    int scol = (l & 3) * 8;

    for (int kk = 0; kk < 8; ++kk) {
        int k0 = kk * 32;
#pragma unroll
        for (int j = 0; j < 2; ++j) {
            int row = w * 32 + j * 16 + srow;
            gload16(A + (size_t)(m0 + row) * CI + k0 + scol, &As[w * 32 + j * 16][0]);
            gload16(Bt + (size_t)(n0 + row) * CI + k0 + scol, &Bs[w * 32 + j * 16][0]);
        }
        __syncthreads();
        bf16x8 af[4], bfr[4];
#pragma unroll
        for (int m = 0; m < 4; ++m) af[m] = *reinterpret_cast<const bf16x8*>(&As[ar + m * 16][kq]);
#pragma unroll
        for (int n = 0; n < 4; ++n) bfr[n] = *reinterpret_cast<const bf16x8*>(&Bs[br + n * 16][kq]);
#pragma unroll
        for (int m = 0; m < 4; ++m)
#pragma unroll
            for (int n = 0; n < 4; ++n)
                acc[m][n] = __builtin_amdgcn_mfma_f32_16x16x32_bf16(af[m], bfr[n], acc[m][n], 0, 0, 0);
        __syncthreads();
    }

    int rbase = m0 + wr * 64 + (l >> 4) * 4;
    int cbase = n0 + wc * 64 + (l & 15);
#pragma unroll
    for (int m = 0; m < 4; ++m)
#pragma unroll
        for (int n = 0; n < 4; ++n)
#pragma unroll
            for (int r = 0; r < 4; ++r) {
                size_t row = rbase + m * 16 + r;
                size_t col = cbase + n * 16;
                if (OUT_BF16)
                    ((unsigned short*)outp)[row * CO + col] = f2b(acc[m][n][r]);
                else
                    ((float*)outp)[row * CO + col] = acc[m][n][r];
            }
}

// ---------------------------------------------------------------------------
// Fused 1x1-conv projection v2: float4 A-loads (512B segments), XOR-swizzled
// pair-packed LDS writes (4-way), register A-prefetch + double-buffered B
// (loads issued before MFMA -> latency hides under compute + barrier drain).
__global__ __launch_bounds__(256) void k_proj(const float* __restrict__ keys,
                                              const float* __restrict__ values,
                                              const unsigned short* __restrict__ wbuf,
                                              const float* __restrict__ bK,
                                              const float* __restrict__ bV,
                                              unsigned short* __restrict__ kp,
                                              unsigned short* __restrict__ vp) {
    __shared__ unsigned short As[128][40];      // pitch 20 dwords, block-XOR swizzled
    __shared__ unsigned short Bs[2][128][32];   // double-buffered W tiles
    int blk = ((blockIdx.x & 7) << 8) | (blockIdx.x >> 3);  // XCD swizzle (bijective)
    int map = blk >> 10;
    int rem = blk & 1023;
    int b = rem >> 8;
    int rem2 = rem & 255;
    int pix0 = (rem2 >> 1) * 128;
    int o0 = (rem2 & 1) * 128;
    const float* X = (map ? values : keys) + (size_t)b * (CI * NPIX);
    const unsigned short* W = wbuf + (size_t)map * 65536;
    const float* bias = map ? bV : bK;
    unsigned short* outp = (map ? vp : kp) + (size_t)b * (NPIX * CO);

    int t = threadIdx.x;
    int w = t >> 6, l = t & 63;
    int wr = w >> 1, wc = w & 1;

    f32x4 acc[4][4];
#pragma unroll
    for (int n = 0; n < 4; ++n) {
        float bv = bias[o0 + wc * 64 + n * 16 + (l & 15)];
#pragma unroll
        for (int m = 0; m < 4; ++m) acc[m][n] = f32x4{bv, bv, bv, bv};
    }

    // A staging: thread covers ch pairs {2cp0,2cp0+1} and {2cp0+16,2cp0+17},
    // pixels pxl..pxl+3 (one float4 per channel row).
    int cp0 = t >> 5;                                   // 0..7
    int pxl = 4 * (t & 31);                             // 0..124
    int fx = ((t & 31) ^ ((t & 31) >> 2)) & 3;          // f(px>>2)
    int colA = cp0 ^ (fx << 2);
    int colB = (cp0 + 8) ^ (fx << 2);
    const float* Xp = X + pix0 + pxl;

    // B staging (global_load_lds): wave w covers rows w*32..w*32+31
    int srow = l >> 2, scol = (l & 3) * 8;

    // fragment geometry
    int ar = wr * 64 + (l & 15);
    int br = wc * 64 + (l & 15);
    int g = l >> 4;           // dword block 0..3
    int kq = g * 8;

    float4 fa0, fa1, fa2, fa3;

#define LOADA(kk)                                                         \
    {                                                                     \
        const float* p_ = Xp + (size_t)((kk) * 32 + 2 * cp0) * NPIX;      \
        fa0 = *(const float4*)(p_);                                       \
        fa1 = *(const float4*)(p_ + NPIX);                                \
        fa2 = *(const float4*)(p_ + 16 * NPIX);                           \
        fa3 = *(const float4*)(p_ + 17 * NPIX);                           \
    }
#define WRITEA()                                                          \
    {                                                                     \
        const float* q0_ = (const float*)&fa0;                            \
        const float* q1_ = (const float*)&fa1;                            \
        const float* q2_ = (const float*)&fa2;                            \
        const float* q3_ = (const float*)&fa3;                            \
        _Pragma("unroll")                                                 \
        for (int j = 0; j < 4; ++j) {                                     \
            unsigned d0_ = (unsigned)f2b(q0_[j]) | ((unsigned)f2b(q1_[j]) << 16); \
            unsigned d1_ = (unsigned)f2b(q2_[j]) | ((unsigned)f2b(q3_[j]) << 16); \
            unsigned* rp_ = (unsigned*)&As[pxl + j][0];                   \
            rp_[colA] = d0_;                                              \
            rp_[colB] = d1_;                                              \
        }                                                                 \
    }
#define LOADB(kk, buf)                                                    \
    {                                                                     \
        int k0_ = (kk) * 32;                                              \
        _Pragma("unroll")                                                 \
        for (int j = 0; j < 2; ++j) {                                     \
            int row_ = w * 32 + j * 16;                                   \
            gload16(W + (size_t)(o0 + row_ + srow) * CI + k0_ + scol,     \
                    &Bs[buf][row_][0]);                                   \
        }                                                                 \
    }

    LOADA(0);
    LOADB(0, 0);
    WRITEA();
    __syncthreads();

    for (int kk = 0; kk < 8; ++kk) {
        if (kk < 7) {
            LOADA(kk + 1);
            LOADB(kk + 1, (kk + 1) & 1);
        }
        bf16x8 af[4], bfr[4];
#pragma unroll
        for (int m = 0; m < 4; ++m) {
            int p = ar + m * 16;
            int gm = (g ^ (((p >> 2) ^ (p >> 4)) & 3)) * 8;
            af[m] = *reinterpret_cast<const bf16x8*>(&As[p][gm]);
        }
#pragma unroll
        for (int n = 0; n < 4; ++n)
            bfr[n] = *reinterpret_cast<const bf16x8*>(&Bs[kk & 1][br + n * 16][kq]);
#pragma unroll
        for (int m = 0; m < 4; ++m)
#pragma unroll
            for (int n = 0; n < 4; ++n)
                acc[m][n] = __builtin_amdgcn_mfma_f32_16x16x32_bf16(af[m], bfr[n], acc[m][n], 0, 0, 0);
        __syncthreads();   // all waves done reading As; drains in-flight loads
        if (kk < 7) {
            WRITEA();
            __syncthreads();  // As(kk+1) ready; Bs other buffer drained here too
        }
    }

    int rbase = wr * 64 + (l >> 4) * 4;
    int cbase = o0 + wc * 64 + (l & 15);
#pragma unroll
    for (int m = 0; m < 4; ++m)
#pragma unroll
        for (int n = 0; n < 4; ++n)
#pragma unroll
            for (int r = 0; r < 4; ++r) {
                size_t row = (size_t)pix0 + rbase + m * 16 + r;
                size_t col = cbase + n * 16;
                outp[row * CO + col] = f2b(acc[m][n][r]);
            }
#undef LOADA
#undef WRITEA
#undef LOADB
}

// ---------------------------------------------------------------------------
// Deformable sampling + attention. One wave per query, 4 ch/lane (uint2 loads).
// XCD-batch clustering: XCD pair {2b,2b+1} owns batch b (L2 locality on maps).
__global__ __launch_bounds__(256) void k_attn(const unsigned short* __restrict__ kp,
                                              const unsigned short* __restrict__ vp,
                                              const unsigned short* __restrict__ qh,
                                              const float* __restrict__ loc,
                                              unsigned short* __restrict__ aout) {
    int t = threadIdx.x;
    int wv = t >> 6, l = t & 63;
    int blk = blockIdx.x;
    int xcd = blk & 7;
    int b = xcd >> 1;
    int idx = ((blk >> 3) << 1) | (xcd & 1);
    int bq = (b << 12) | (idx << 2) | wv;

    float qv[4];
    {
        uint2 qr = *reinterpret_cast<const uint2*>(qh + (size_t)bq * CO + l * 4);
        b2f2(qr.x, qv[0], qv[1]);
        b2f2(qr.y, qv[2], qv[3]);
    }
    const unsigned short* kb = kp + (size_t)b * NPIX * CO;
    const unsigned short* vb = vp + (size_t)b * NPIX * CO;
    const float* lq = loc + (size_t)bq * (NS * 2);
    int choff = l * 4;

    float m = -3.0e38f, lsum = 0.f;
    float o0 = 0.f, o1 = 0.f, o2 = 0.f, o3 = 0.f;

#pragma unroll
    for (int s = 0; s < NS; ++s) {
        float x = lq[2 * s];
        float y = lq[2 * s + 1];
        float gx = (x + 1.f) * (WFEAT * 0.5f) - 0.5f;
        float gy = (y + 1.f) * (HFEAT * 0.5f) - 0.5f;
        float x0f = floorf(gx), y0f = floorf(gy);
        int x0 = (int)x0f, y0 = (int)y0f;
        float wx1 = gx - x0f, wy1 = gy - y0f;
        float wx0 = 1.f - wx1, wy0 = 1.f - wy1;
        bool xa = (x0 >= 0) && (x0 < WFEAT);
        bool xb = (x0 + 1 >= 0) && (x0 + 1 < WFEAT);
        bool ya = (y0 >= 0) && (y0 < HFEAT);
        bool yb = (y0 + 1 >= 0) && (y0 + 1 < HFEAT);
        size_t i00 = (size_t)(y0 * WFEAT + x0) * CO + choff;

        uint2 z = make_uint2(0u, 0u);
        uint2 k00 = z, k01 = z, k10 = z, k11 = z;
        uint2 v00 = z, v01 = z, v10 = z, v11 = z;
        if (xa && ya) { k00 = *(const uint2*)(kb + i00);                 v00 = *(const uint2*)(vb + i00); }
        if (xb && ya) { k01 = *(const uint2*)(kb + i00 + CO);            v01 = *(const uint2*)(vb + i00 + CO); }
        if (xa && yb) { k10 = *(const uint2*)(kb + i00 + WFEAT * CO);    v10 = *(const uint2*)(vb + i00 + WFEAT * CO); }
        if (xb && yb) { k11 = *(const uint2*)(kb + i00 + (WFEAT+1)*CO);  v11 = *(const uint2*)(vb + i00 + (WFEAT+1)*CO); }

        float a0, a1, b0, b1, c0, c1, d0, d1;
        float ks[4], vs[4];
        b2f2(k00.x, a0, a1); b2f2(k01.x, b0, b1); b2f2(k10.x, c0, c1); b2f2(k11.x, d0, d1);
        ks[0] = fmaf(fmaf(b0, wx1, a0 * wx0), wy0, fmaf(d0, wx1, c0 * wx0) * wy1);
        ks[1] = fmaf(fmaf(b1, wx1, a1 * wx0), wy0, fmaf(d1, wx1, c1 * wx0) * wy1);
        b2f2(k00.y, a0, a1); b2f2(k01.y, b0, b1); b2f2(k10.y, c0, c1); b2f2(k11.y, d0, d1);
        ks[2] = fmaf(fmaf(b0, wx1, a0 * wx0), wy0, fmaf(d0, wx1, c0 * wx0) * wy1);
        ks[3] = fmaf(fmaf(b1, wx1, a1 * wx0), wy0, fmaf(d1, wx1, c1 * wx0) * wy1);
        b2f2(v00.x, a0, a1); b2f2(v01.x, b0, b1); b2f2(v10.x, c0, c1); b2f2(v11.x, d0, d1);
        vs[0] = fmaf(fmaf(b0, wx1, a0 * wx0), wy0, fmaf(d0, wx1, c0 * wx0) * wy1);
        vs[1] = fmaf(fmaf(b1, wx1, a1 * wx0), wy0, fmaf(d1, wx1, c1 * wx0) * wy1);
        b2f2(v00.y, a0, a1); b2f2(v01.y, b0, b1); b2f2(v10.y, c0, c1); b2f2(v11.y, d0, d1);
        vs[2] = fmaf(fmaf(b0, wx1, a0 * wx0), wy0, fmaf(d0, wx1, c0 * wx0) * wy1);
        vs[3] = fmaf(fmaf(b1, wx1, a1 * wx0), wy0, fmaf(d1, wx1, c1 * wx0) * wy1);

        float p = fmaf(qv[0], ks[0], fmaf(qv[1], ks[1], fmaf(qv[2], ks[2], qv[3] * ks[3])));
        p += __shfl_xor(p, 1);
        p += __shfl_xor(p, 2);
        p += __shfl_xor(p, 4);
        float lg = p * 0.0625f;

        float nm = fmaxf(m, lg);
        float sc = __expf(m - nm);
        float wgt = __expf(lg - nm);
        lsum = fmaf(lsum, sc, wgt);
        o0 = fmaf(o0, sc, wgt * vs[0]);
        o1 = fmaf(o1, sc, wgt * vs[1]);
        o2 = fmaf(o2, sc, wgt * vs[2]);
        o3 = fmaf(o3, sc, wgt * vs[3]);
        m = nm;
    }

    float inv = 1.f / lsum;
    uint2 pk;
    pk.x = ((unsigned)f2b(o0 * inv)) | (((unsigned)f2b(o1 * inv)) << 16);
    pk.y = ((unsigned)f2b(o2 * inv)) | (((unsigned)f2b(o3 * inv)) << 16);
    *reinterpret_cast<uint2*>(aout + (size_t)bq * CO + choff) = pk;
}

// ---------------------------------------------------------------------------
extern "C" void kernel_launch(void* const* d_in, const int* in_sizes, int n_in,
                              void* d_out, int out_size, void* d_ws, size_t ws_size,
                              hipStream_t stream) {
    (void)in_sizes; (void)n_in; (void)out_size; (void)ws_size;
    const float* queries = (const float*)d_in[0];
    const float* keys    = (const float*)d_in[1];
    const float* values  = (const float*)d_in[2];
    const float* W_loc   = (const float*)d_in[3];
    const float* b_loc   = (const float*)d_in[4];
    const float* W_q     = (const float*)d_in[5];
    const float* b_q     = (const float*)d_in[6];
    const float* W_k     = (const float*)d_in[7];
    const float* b_k     = (const float*)d_in[8];
    const float* W_v     = (const float*)d_in[9];
    const float* b_v     = (const float*)d_in[10];
    const float* W_o     = (const float*)d_in[11];
    const float* b_o     = (const float*)d_in[12];
    float* out = (float*)d_out;

    char* ws = (char*)d_ws;
    unsigned short* kp   = (unsigned short*)(ws);                  // 32 MB
    unsigned short* vp   = (unsigned short*)(ws + 33554432);       // 32 MB
    unsigned short* qbf  = (unsigned short*)(ws + 67108864);       // 8 MB
    unsigned short* aout = (unsigned short*)(ws + 67108864);       // reuses qbf (dead by k_attn)
    unsigned short* qh   = (unsigned short*)(ws + 75497472);       // 8 MB
    float* locb          = (float*)(ws + 83886080);                // 1 MB
    unsigned short* wbuf = (unsigned short*)(ws + 84934656);       // 512 KB

    k_prep_w<<<dim3(64, 4), 256, 0, stream>>>(W_k, W_v, W_q, W_o, wbuf);
    k_cvt<<<dim3(2048), 256, 0, stream>>>(queries, qbf);
    k_loc<<<dim3(512), 256, 0, stream>>>(queries, W_loc, b_loc, locb);
    k_gemm<1><<<dim3(256), 256, 0, stream>>>(qbf, wbuf + 131072, b_q, qh);
    k_proj<<<dim3(2048), 256, 0, stream>>>(keys, values, wbuf, b_k, b_v, kp, vp);
    k_attn<<<dim3(NB * NQ / 4), 256, 0, stream>>>(kp, vp, qh, locb, aout);
    k_gemm<0><<<dim3(256), 256, 0, stream>>>(aout, wbuf + 196608, b_o, out);
}